// Round 9
// baseline (147.167 us; speedup 1.0000x reference)
//
#include <hip/hip_runtime.h>

// Problem: B=16384, X_DIM=1024, K=64, fp32 in/out.
// out[b] = 0.5 * ( sum_k (x_b . V[:,k])^2  -  sum_i x_bi^2 w_i ),  w_i = sum_k V[i][k]^2
//
// R9: pure fp32 VALU path engineered for 32 waves/CU (the only measured scaling
// law this session: R1 had VALUBusy ~= Occupancy, i.e. issue-bound; time ~ 1/waves).
//  - lane = k (64 k's = 64 lanes): V loads perfectly coalesced; x broadcast from
//    a 33 KB LDS tile (ds_read_b128 same-address = conflict-free broadcast).
//  - y[32 rows] per lane -> ~55 VGPR -> 8 waves/SIMD. Grid 2048 x 256 thr.
//  - i-quarter split across blocks: y-partials to ws (16 MB), finish kernel
//    sums quarters BEFORE squaring. z computed during x staging (free).

typedef float f32x4 __attribute__((ext_vector_type(4)));

constexpr int XD = 1024;
constexpr int KD = 64;
constexpr int XPITCH = 260;   // LDS row pitch (floats): 4r bank offset -> conflict-free staging

// ---- prep: wc[i] = sum_k V[i][k]^2 (1024 parallel threads, independent loads) ----
__global__ void prep_w(const float* __restrict__ v, float* __restrict__ wc) {
    int i = blockIdx.x * 256 + threadIdx.x;   // grid 4 x 256 -> 0..1023
    const f32x4* vp = (const f32x4*)(v + (size_t)i * KD);
    f32x4 tv[16];
#pragma unroll
    for (int q = 0; q < 16; ++q) tv[q] = vp[q];
    float s = 0.f;
#pragma unroll
    for (int q = 0; q < 16; ++q) {
        s = fmaf(tv[q].x, tv[q].x, s); s = fmaf(tv[q].y, tv[q].y, s);
        s = fmaf(tv[q].z, tv[q].z, s); s = fmaf(tv[q].w, tv[q].w, s);
    }
    wc[i] = s;
}

// ---- main: block = (row-group g: 32 rows) x (i-quarter q: 256 i's) ----
// 4 waves = 4 i-windows of 64. lane = k. y[32] fp32 accumulators per lane.
__global__ __launch_bounds__(256, 8)
void cross_valu(const float* __restrict__ x, const float* __restrict__ v,
                const float* __restrict__ wc,
                float* __restrict__ wsy, float* __restrict__ wsz) {
    __shared__ float xl[32 * XPITCH];   // 33,280 B x-tile; front reused as combine area
    __shared__ float zbuf[32][8];       // 1 KB z staging partials

    const int tid  = threadIdx.x;
    const int lane = tid & 63;
    const int w    = tid >> 6;              // wave 0..3 = i-window
    const int g    = blockIdx.x >> 2;       // row-group 0..511
    const int q    = blockIdx.x & 3;        // i-quarter 0..3
    const int row0 = g * 32;
    const int qi0  = q * 256;

    // ---- stage x[32][256] into LDS; compute z partials on the fly ----
    {
        const int r = tid >> 3, c = tid & 7;     // thread covers row r, 32-i chunk c
        const float* xp = x + (size_t)(row0 + r) * XD + qi0 + c * 32;
        const float* wp = wc + qi0 + c * 32;
        float zp = 0.f;
#pragma unroll
        for (int j = 0; j < 8; ++j) {
            f32x4 xv = *(const f32x4*)(xp + j * 4);
            f32x4 wv = *(const f32x4*)(wp + j * 4);
            *(f32x4*)&xl[r * XPITCH + c * 32 + j * 4] = xv;
            zp = fmaf(xv.x * xv.x, wv.x, zp);
            zp = fmaf(xv.y * xv.y, wv.y, zp);
            zp = fmaf(xv.z * xv.z, wv.z, zp);
            zp = fmaf(xv.w * xv.w, wv.w, zp);
        }
        zbuf[r][c] = zp;
    }
    __syncthreads();

    // ---- compute: y[r] += x[r][i] * V[i][lane], i in this wave's 64-window ----
    float y[32];
#pragma unroll
    for (int r = 0; r < 32; ++r) y[r] = 0.f;

    const float* vbase = v + (size_t)(qi0 + w * 64) * KD + lane;

#pragma unroll 2
    for (int grp = 0; grp < 16; ++grp) {          // 4 i's per group
        const int iL = w * 64 + grp * 4;
        float v0 = vbase[(grp * 4 + 0) * KD];     // coalesced: 64 lanes = 256 B line
        float v1 = vbase[(grp * 4 + 1) * KD];
        float v2 = vbase[(grp * 4 + 2) * KD];
        float v3 = vbase[(grp * 4 + 3) * KD];
#pragma unroll
        for (int r = 0; r < 32; ++r) {
            f32x4 xr = *(const f32x4*)&xl[r * XPITCH + iL];   // broadcast read
            float a = fmaf(xr.x, v0, y[r]);
            a = fmaf(xr.y, v1, a);
            a = fmaf(xr.z, v2, a);
            y[r] = fmaf(xr.w, v3, a);
        }
    }
    __syncthreads();   // all xl reads done; safe to reuse as combine area

    // ---- combine the 4 waves' i-window partials (sum BEFORE squaring) ----
    float* comb = xl;   // 3 slabs x 32 rows x 64 lanes = 6144 floats
    if (w > 0) {
        const int s = w - 1;
#pragma unroll
        for (int r = 0; r < 32; ++r) comb[(s * 32 + r) * 64 + lane] = y[r];
    }
    __syncthreads();

    if (w == 0) {
#pragma unroll
        for (int s = 0; s < 3; ++s)
#pragma unroll
            for (int r = 0; r < 32; ++r) y[r] += comb[(s * 32 + r) * 64 + lane];

        // write quarter-partial y slab: wsy[block][r][k]
        float* yout = wsy + (size_t)blockIdx.x * 32 * 64;
#pragma unroll
        for (int r = 0; r < 32; ++r) yout[r * 64 + lane] = y[r];

        // z: sum the 8 staging partials per row; write quarter-partial z
        if (lane < 32) {
            const f32x4* zp4 = (const f32x4*)&zbuf[lane][0];
            f32x4 a = zp4[0], b = zp4[1];
            float z = (a.x + a.y + a.z + a.w) + (b.x + b.y + b.z + b.w);
            wsz[(size_t)blockIdx.x * 32 + lane] = z;
        }
    }
}

// ---- finish: out[row] = 0.5 * ( sum_k (sum_q y_q)^2 - sum_q z_q ) ----
__global__ __launch_bounds__(256, 8)
void finish(const float* __restrict__ wsy, const float* __restrict__ wsz,
            float* __restrict__ out) {
    const int t = threadIdx.x;
    const int rowl = t >> 2, part = t & 3;        // 64 rows x 4 k-chunks of 16
    const int row = blockIdx.x * 64 + rowl;
    const int g = row >> 5, r = row & 31;

    f32x4 acc[4] = {f32x4{0,0,0,0}, f32x4{0,0,0,0}, f32x4{0,0,0,0}, f32x4{0,0,0,0}};
#pragma unroll
    for (int q = 0; q < 4; ++q) {
        const float* base = wsy + ((size_t)(g * 4 + q) * 32 + r) * 64 + part * 16;
#pragma unroll
        for (int u = 0; u < 4; ++u) acc[u] += *(const f32x4*)(base + u * 4);
    }
    float p = 0.f;
#pragma unroll
    for (int u = 0; u < 4; ++u) {
        p = fmaf(acc[u].x, acc[u].x, p);
        p = fmaf(acc[u].y, acc[u].y, p);
        p = fmaf(acc[u].z, acc[u].z, p);
        p = fmaf(acc[u].w, acc[u].w, p);
    }
    // combine the 4 k-chunks (xor masks < 4 stay within the 4-thread group)
    p += __shfl_xor(p, 1);
    p += __shfl_xor(p, 2);

    if (part == 0) {
        float z = 0.f;
#pragma unroll
        for (int q = 0; q < 4; ++q) z += wsz[(size_t)(g * 4 + q) * 32 + r];
        out[row] = 0.5f * (p - z);
    }
}

extern "C" void kernel_launch(void* const* d_in, const int* in_sizes, int n_in,
                              void* d_out, int out_size, void* d_ws, size_t ws_size,
                              hipStream_t stream) {
    const float* x = (const float*)d_in[0];      // (16384, 1024) fp32
    const float* v = (const float*)d_in[1];      // (1024, 64) fp32
    float* out = (float*)d_out;                  // (16384, 1) fp32

    float* wc  = (float*)d_ws;                                   //   4096 B
    float* wsz = (float*)((char*)d_ws + 4096);                   // 262144 B (2048*32*4)
    float* wsy = (float*)((char*)d_ws + 4096 + 262144);          //  16 MiB (2048*2048*4)

    const int B = in_sizes[0] / XD;              // 16384

    hipLaunchKernelGGL(prep_w,     dim3(4),            dim3(256), 0, stream, v, wc);
    hipLaunchKernelGGL(cross_valu, dim3((B / 32) * 4), dim3(256), 0, stream,
                       x, v, wc, wsy, wsz);
    hipLaunchKernelGGL(finish,     dim3(B / 64),       dim3(256), 0, stream,
                       wsy, wsz, out);
}

// Round 10
// 118.257 us; speedup vs baseline: 1.2445x; 1.2445x over previous
//
#include <hip/hip_runtime.h>

// Problem: B=16384, X_DIM=1024, K=64, fp32 in/out.
// out[b] = 0.5 * ( sum_k (x_b . V[:,k])^2  -  sum_i x_bi^2 w_i ),  w_i = sum_k V[i][k]^2
//
// R10: 32x32x16 bf16 MFMA, wave = 32 rows x 64 cols, 8-way in-block K-split.
// Halves B-fragment traffic (128 MB) and VMEM instr count vs R7 at the SAME
// 16 waves/CU. Trunc hi/lo split (3 products, fp32 acc). No finish kernel.
//
// Layouts (guide m74/m101 + R2-verified analogy):
//   A: lane l holds A[m=l&31][k=(l>>5)*8+j], j=0..7
//   B: lane l holds B[k=(l>>5)*8+j][n=l&31]
//   C/D: col=l&31, row=(r&3)+8*(r>>2)+4*(l>>5), r=0..15

typedef short short8 __attribute__((ext_vector_type(8)));    // 8 bf16 = 4 VGPRs
typedef float f32x4  __attribute__((ext_vector_type(4)));
typedef float f32x16 __attribute__((ext_vector_type(16)));

constexpr int XD = 1024;
constexpr int KD = 64;

static __device__ __forceinline__ unsigned short f2bf(float f) {
    union { float f; unsigned u; } v; v.f = f;
    unsigned r = v.u + 0x7FFFu + ((v.u >> 16) & 1u);   // RNE
    return (unsigned short)(r >> 16);
}
static __device__ __forceinline__ float bf2f(unsigned short h) {
    union { unsigned u; float f; } v; v.u = ((unsigned)h) << 16;
    return v.f;
}
static __device__ __forceinline__ unsigned fbits(float f) {
    union { float f; unsigned u; } v; v.f = f; return v.u;
}
static __device__ __forceinline__ float bitsf(unsigned u) {
    union { unsigned u; float f; } v; v.u = u; return v.f;
}

// ---- prep: blocks 0..31 -> 32x32x16 B-fragments (hi/lo); 32..35 -> w ----
// bh layout: [kt:64][t:2][lane:64][j:8] bf16  (131072 B); bl same; wc 4 KB.
__global__ void prep_kernel(const float* __restrict__ v,
                            unsigned short* __restrict__ bh,
                            unsigned short* __restrict__ bl,
                            float* __restrict__ wc) {
    if (blockIdx.x < 32) {
        int idx = blockIdx.x * 256 + threadIdx.x;   // 0..8191
        int kt = idx >> 7;          // K-16 tile 0..63
        int rem = idx & 127;
        int t = rem >> 6;           // col frag 0..1
        int l = rem & 63;
        int n = t * 32 + (l & 31);
        int kbase = (l >> 5) * 8;
        size_t fo = ((size_t)(kt * 2 + t) * 64 + l) * 8;
#pragma unroll
        for (int j = 0; j < 8; ++j) {
            float val = v[(size_t)(kt * 16 + kbase + j) * KD + n];
            unsigned short h = f2bf(val);
            bh[fo + j] = h;
            bl[fo + j] = f2bf(val - bf2f(h));
        }
    } else {
        int i = (blockIdx.x - 32) * 256 + threadIdx.x;   // 0..1023
        const f32x4* vp = (const f32x4*)(v + (size_t)i * KD);
        f32x4 tv[16];
#pragma unroll
        for (int q = 0; q < 16; ++q) tv[q] = vp[q];
        float s = 0.f;
#pragma unroll
        for (int q = 0; q < 16; ++q) {
            s = fmaf(tv[q].x, tv[q].x, s); s = fmaf(tv[q].y, tv[q].y, s);
            s = fmaf(tv[q].z, tv[q].z, s); s = fmaf(tv[q].w, tv[q].w, s);
        }
        wc[i] = s;
    }
}

// ---- main: 512 thr / 8 waves; block = 32 rows; wave = 32 rows x 128 i ----
__global__ __launch_bounds__(512, 4)
void cross_r10(const float* __restrict__ x,
               const unsigned short* __restrict__ bh,
               const unsigned short* __restrict__ bl,
               const float* __restrict__ wc,
               float* __restrict__ out) {
    __shared__ float wlds[XD];           //  4096 B
    __shared__ float comb[7][32][64];    // 57344 B  [slot][f*16+r][lane] -> conflict-free
    __shared__ float zbm[7][32];         //   896 B   (total ~61 KB -> 2 blocks/CU)

    const int tid = threadIdx.x;
    const int l = tid & 63;
    const int w = tid >> 6;              // wave 0..7 = K-split (128 i each)
    const int m = l & 31, h = l >> 5;
    const int row0 = blockIdx.x * 32;

    // stage w (512 thr x float2, coalesced aligned)
    *(float2*)&wlds[tid * 2] = *(const float2*)(wc + tid * 2);
    __syncthreads();

    f32x16 acc0 = {}, acc1 = {};
    float z = 0.f;

    const short8* bhp = (const short8*)bh;
    const short8* blp = (const short8*)bl;
    const float* xrow = x + (size_t)(row0 + m) * XD + h * 8;

#pragma unroll
    for (int ii = 0; ii < 8; ++ii) {
        const int kt = w * 8 + ii;       // K-16 tile index
        const int i0 = kt * 16;

        f32x4 xa = *(const f32x4*)(xrow + i0);        // k = h*8 + 0..3
        f32x4 xb = *(const f32x4*)(xrow + i0 + 4);    // k = h*8 + 4..7

        const float* wp = &wlds[i0 + h * 8];
        f32x4 wa = *(const f32x4*)wp, wb = *(const f32x4*)(wp + 4);
        float xs[8] = {xa.x, xa.y, xa.z, xa.w, xb.x, xb.y, xb.z, xb.w};
        z = fmaf(xs[0]*xs[0], wa.x, z); z = fmaf(xs[1]*xs[1], wa.y, z);
        z = fmaf(xs[2]*xs[2], wa.z, z); z = fmaf(xs[3]*xs[3], wa.w, z);
        z = fmaf(xs[4]*xs[4], wb.x, z); z = fmaf(xs[5]*xs[5], wb.y, z);
        z = fmaf(xs[6]*xs[6], wb.z, z); z = fmaf(xs[7]*xs[7], wb.w, z);

        // truncation split + v_perm pack (hi16 pairs; lo = exact residual)
        unsigned ahp[4], alp[4];
#pragma unroll
        for (int jp = 0; jp < 4; ++jp) {
            unsigned u0 = fbits(xs[2 * jp]), u1 = fbits(xs[2 * jp + 1]);
            ahp[jp] = __builtin_amdgcn_perm(u1, u0, 0x07060302u);
            float l0 = xs[2 * jp]     - bitsf(u0 & 0xFFFF0000u);
            float l1 = xs[2 * jp + 1] - bitsf(u1 & 0xFFFF0000u);
            alp[jp] = __builtin_amdgcn_perm(fbits(l1), fbits(l0), 0x07060302u);
        }
        short8 ah, al_;
#pragma unroll
        for (int jp = 0; jp < 4; ++jp) {
            ah[2*jp]   = (short)(ahp[jp] & 0xFFFF); ah[2*jp+1]  = (short)(ahp[jp] >> 16);
            al_[2*jp]  = (short)(alp[jp] & 0xFFFF); al_[2*jp+1] = (short)(alp[jp] >> 16);
        }

        const size_t fbase = (size_t)(kt * 2) * 64 + l;
        short8 vh0 = bhp[fbase],      vl0 = blp[fbase];        // cols 0..31
        short8 vh1 = bhp[fbase + 64], vl1 = blp[fbase + 64];   // cols 32..63

        acc0 = __builtin_amdgcn_mfma_f32_32x32x16_bf16(ah,  vh0, acc0, 0, 0, 0);
        acc1 = __builtin_amdgcn_mfma_f32_32x32x16_bf16(ah,  vh1, acc1, 0, 0, 0);
        acc0 = __builtin_amdgcn_mfma_f32_32x32x16_bf16(ah,  vl0, acc0, 0, 0, 0);
        acc1 = __builtin_amdgcn_mfma_f32_32x32x16_bf16(ah,  vl1, acc1, 0, 0, 0);
        acc0 = __builtin_amdgcn_mfma_f32_32x32x16_bf16(al_, vh0, acc0, 0, 0, 0);
        acc1 = __builtin_amdgcn_mfma_f32_32x32x16_bf16(al_, vh1, acc1, 0, 0, 0);
    }

    // z: combine the two k-halves -> full z for row m over this wave's i-range
    z += __shfl_xor(z, 32);

    // ---- combine the 8 K-split partials (sum BEFORE squaring) ----
    if (w > 0) {
        const int s = w - 1;
#pragma unroll
        for (int r = 0; r < 16; ++r) {
            comb[s][r][l]      = acc0[r];
            comb[s][16 + r][l] = acc1[r];
        }
        if (l < 32) zbm[s][l] = z;
    }
    __syncthreads();

    if (w == 0) {
#pragma unroll
        for (int s = 0; s < 7; ++s) {
#pragma unroll
            for (int r = 0; r < 16; ++r) {
                acc0[r] += comb[s][r][l];
                acc1[r] += comb[s][16 + r][l];
            }
            z += zbm[s][m];
        }

        // p[r] = sum over all 64 cols of y[row(r)]^2 ; butterfly over 32-lane half
        float p[16];
#pragma unroll
        for (int r = 0; r < 16; ++r)
            p[r] = fmaf(acc0[r], acc0[r], acc1[r] * acc1[r]);
#pragma unroll
        for (int mask = 1; mask < 32; mask <<= 1)
#pragma unroll
            for (int r = 0; r < 16; ++r) p[r] += __shfl_xor(p[r], mask);

        // row = (r&3) + 8*(r>>2) + 4h ; lane l writes row m=l&31 iff h matches
        if (h == ((l >> 2) & 1)) {
            const int r = (m & 3) | (((m >> 3) & 3) << 2);
            out[row0 + m] = 0.5f * (p[r] - z);
        }
    }
}

extern "C" void kernel_launch(void* const* d_in, const int* in_sizes, int n_in,
                              void* d_out, int out_size, void* d_ws, size_t ws_size,
                              hipStream_t stream) {
    const float* x = (const float*)d_in[0];      // (16384, 1024) fp32
    const float* v = (const float*)d_in[1];      // (1024, 64) fp32
    float* out = (float*)d_out;                  // (16384, 1) fp32

    unsigned short* bh = (unsigned short*)d_ws;                    // 131072 B
    unsigned short* bl = (unsigned short*)((char*)d_ws + 131072);  // 131072 B
    float* wc = (float*)((char*)d_ws + 262144);                    //   4096 B

    const int B = in_sizes[0] / XD;              // 16384

    hipLaunchKernelGGL(prep_kernel, dim3(36), dim3(256), 0, stream, v, bh, bl, wc);
    hipLaunchKernelGGL(cross_r10, dim3(B / 32), dim3(512), 0, stream,
                       x, bh, bl, wc, out);
}

// Round 11
// 111.868 us; speedup vs baseline: 1.3155x; 1.0571x over previous
//
#include <hip/hip_runtime.h>

// Problem: B=16384, X_DIM=1024, K=64, fp32 in/out.
// out[b] = 0.5 * ( sum_k (x_b . V[:,k])^2  -  sum_i x_bi^2 w_i ),  w_i = sum_k V[i][k]^2
//
// R11: clean B-fragment-traffic experiment. Two-phase:
//  partial: block = 128 rows x 128-i slice; stages its 32 KB V-frag slice in LDS
//           ONCE (global frag traffic 256->32 MB vs R7), wave = 16 rows end-to-end
//           (no in-block combine). y-partials (32 MB) + z-partials to ws.
//  finish:  sums the 8 slice partials per row BEFORE squaring, subtracts z.
// Same MFMA shape (16x16x32), same trunc repack, same 16 waves/CU as R7.

typedef short short8 __attribute__((ext_vector_type(8)));   // 8 bf16 = 4 VGPRs
typedef float f32x4 __attribute__((ext_vector_type(4)));

constexpr int XD = 1024;
constexpr int KD = 64;

static __device__ __forceinline__ unsigned short f2bf(float f) {
    union { float f; unsigned u; } v; v.f = f;
    unsigned r = v.u + 0x7FFFu + ((v.u >> 16) & 1u);   // RNE
    return (unsigned short)(r >> 16);
}
static __device__ __forceinline__ float bf2f(unsigned short h) {
    union { unsigned u; float f; } v; v.u = ((unsigned)h) << 16;
    return v.f;
}
static __device__ __forceinline__ unsigned fbits(float f) {
    union { float f; unsigned u; } v; v.f = f; return v.u;
}
static __device__ __forceinline__ float bitsf(unsigned u) {
    union { unsigned u; float f; } v; v.u = u; return v.f;
}

// ---- prep: blocks 0..31 build bf16 hi/lo B-fragments (RNE); 32..35 build w ----
// B-fragment layout (mfma_f32_16x16x32_bf16): lane l holds B[k=(l>>4)*8+j][n=l&15]
// bh: [it:32][t:4][lane:64][j:8] bf16 (131072 B); bl same; wc[1024] fp32.
__global__ void prep_kernel(const float* __restrict__ v,
                            unsigned short* __restrict__ bh,
                            unsigned short* __restrict__ bl,
                            float* __restrict__ wc) {
    if (blockIdx.x < 32) {
        int idx = blockIdx.x * 256 + threadIdx.x;
        int it = idx >> 8;
        int r  = idx & 255;
        int t  = r >> 6;
        int l  = r & 63;
        int q  = l >> 4, m = l & 15;
        int base_i = it * 32 + q * 8;
        int n = t * 16 + m;
        size_t fo = ((size_t)(it * 4 + t) * 64 + l) * 8;
#pragma unroll
        for (int j = 0; j < 8; ++j) {
            float val = v[(size_t)(base_i + j) * KD + n];
            unsigned short h = f2bf(val);
            bh[fo + j] = h;
            bl[fo + j] = f2bf(val - bf2f(h));
        }
    } else {
        int i = (blockIdx.x - 32) * 256 + threadIdx.x;   // 0..1023
        const f32x4* vp = (const f32x4*)(v + (size_t)i * KD);
        f32x4 tv[16];
#pragma unroll
        for (int q = 0; q < 16; ++q) tv[q] = vp[q];
        float s = 0.f;
#pragma unroll
        for (int q = 0; q < 16; ++q) {
            s = fmaf(tv[q].x, tv[q].x, s); s = fmaf(tv[q].y, tv[q].y, s);
            s = fmaf(tv[q].z, tv[q].z, s); s = fmaf(tv[q].w, tv[q].w, s);
        }
        wc[i] = s;
    }
}

// ---- partial: grid = 128 row-groups x 8 slices; 512 thr = 8 waves x 16 rows ----
__global__ __launch_bounds__(512, 4)
void partial(const float* __restrict__ x,
             const unsigned short* __restrict__ bh,
             const unsigned short* __restrict__ bl,
             const float* __restrict__ wc,
             float* __restrict__ wsy, float* __restrict__ wsz) {
    __shared__ short lbh[4 * 4 * 64 * 8];   // 16 KB: this slice's hi frags [it4][t][l][j]
    __shared__ short lbl[4 * 4 * 64 * 8];   // 16 KB: lo frags
    __shared__ float wlds[XD];              //  4 KB

    const int tid = threadIdx.x;
    const int l = tid & 63;
    const int w = tid >> 6;            // wave 0..7 -> rows w*16..w*16+15
    const int q = l >> 4, m = l & 15;
    const int g = blockIdx.x >> 3;     // row-group 0..127
    const int s = blockIdx.x & 7;      // i-slice 0..7 (128 i each)
    const int row0 = g * 128;
    const int i0 = s * 128;

    // stage wc (512 thr x float2) and this slice's 32 KB of fragments (b128 x 4)
    *(float2*)&wlds[tid * 2] = *(const float2*)(wc + tid * 2);
    {
        const f32x4* sh = (const f32x4*)(bh + (size_t)s * 8192);   // 4 it-chunks x 2048 shorts
        const f32x4* sl = (const f32x4*)(bl + (size_t)s * 8192);
        f32x4* dh = (f32x4*)lbh;
        f32x4* dl = (f32x4*)lbl;
#pragma unroll
        for (int p = 0; p < 2; ++p) {
            dh[p * 512 + tid] = sh[p * 512 + tid];
            dl[p * 512 + tid] = sl[p * 512 + tid];
        }
    }
    __syncthreads();

    f32x4 ch[4], cl1[4], cl2[4];
#pragma unroll
    for (int t = 0; t < 4; ++t) {
        ch[t]  = f32x4{0.f, 0.f, 0.f, 0.f};
        cl1[t] = f32x4{0.f, 0.f, 0.f, 0.f};
        cl2[t] = f32x4{0.f, 0.f, 0.f, 0.f};
    }
    float z = 0.f;

    const short8* lbh8 = (const short8*)lbh;
    const short8* lbl8 = (const short8*)lbl;
    const float* xrow = x + (size_t)(row0 + w * 16 + m) * XD + i0 + q * 8;

#pragma unroll
    for (int it = 0; it < 4; ++it) {
        f32x4 xa = *(const f32x4*)(xrow + it * 32);
        f32x4 xb = *(const f32x4*)(xrow + it * 32 + 4);

        const float* wp = &wlds[i0 + it * 32 + q * 8];
        f32x4 wa = *(const f32x4*)wp, wb = *(const f32x4*)(wp + 4);
        float xs[8] = {xa.x, xa.y, xa.z, xa.w, xb.x, xb.y, xb.z, xb.w};
        z = fmaf(xs[0]*xs[0], wa.x, z); z = fmaf(xs[1]*xs[1], wa.y, z);
        z = fmaf(xs[2]*xs[2], wa.z, z); z = fmaf(xs[3]*xs[3], wa.w, z);
        z = fmaf(xs[4]*xs[4], wb.x, z); z = fmaf(xs[5]*xs[5], wb.y, z);
        z = fmaf(xs[6]*xs[6], wb.z, z); z = fmaf(xs[7]*xs[7], wb.w, z);

        // truncation split + v_perm pack (hi16 pairs; lo = exact residual)
        unsigned ahp[4], alp[4];
#pragma unroll
        for (int jp = 0; jp < 4; ++jp) {
            unsigned u0 = fbits(xs[2 * jp]), u1 = fbits(xs[2 * jp + 1]);
            ahp[jp] = __builtin_amdgcn_perm(u1, u0, 0x07060302u);
            float l0 = xs[2 * jp]     - bitsf(u0 & 0xFFFF0000u);
            float l1 = xs[2 * jp + 1] - bitsf(u1 & 0xFFFF0000u);
            alp[jp] = __builtin_amdgcn_perm(fbits(l1), fbits(l0), 0x07060302u);
        }
        short8 ah, al_;
#pragma unroll
        for (int jp = 0; jp < 4; ++jp) {
            ah[2*jp]   = (short)(ahp[jp] & 0xFFFF); ah[2*jp+1]  = (short)(ahp[jp] >> 16);
            al_[2*jp]  = (short)(alp[jp] & 0xFFFF); al_[2*jp+1] = (short)(alp[jp] >> 16);
        }

        const int fb = (it * 4) * 64 + l;   // short8 index; lane-contiguous -> conflict-free b128
#pragma unroll
        for (int t = 0; t < 4; ++t) {
            short8 vh = lbh8[fb + t * 64];
            short8 vl = lbl8[fb + t * 64];
            ch[t]  = __builtin_amdgcn_mfma_f32_16x16x32_bf16(ah,  vh, ch[t],  0, 0, 0);
            cl1[t] = __builtin_amdgcn_mfma_f32_16x16x32_bf16(ah,  vl, cl1[t], 0, 0, 0);
            cl2[t] = __builtin_amdgcn_mfma_f32_16x16x32_bf16(al_, vh, cl2[t], 0, 0, 0);
        }
    }

    f32x4 cs[4];
#pragma unroll
    for (int t = 0; t < 4; ++t) cs[t] = ch[t] + cl1[t] + cl2[t];

    // z: sum over the 4 q-chunk lanes of each row -> lanes 0..15 hold rows 0..15
    z += __shfl_xor(z, 16);
    z += __shfl_xor(z, 32);

    // write y-partials: C layout col=l&15, row=q*4+reg
    float* yb = wsy + ((size_t)s * 16384 + row0 + w * 16) * 64;
#pragma unroll
    for (int t = 0; t < 4; ++t)
#pragma unroll
        for (int r = 0; r < 4; ++r)
            yb[(q * 4 + r) * 64 + t * 16 + m] = cs[t][r];

    if (l < 16) wsz[(size_t)s * 16384 + row0 + w * 16 + l] = z;
}

// ---- finish: out[row] = 0.5 * ( sum_k (sum_s y_s)^2 - sum_s z_s ) ----
__global__ __launch_bounds__(256, 8)
void finish(const float* __restrict__ wsy, const float* __restrict__ wsz,
            float* __restrict__ out) {
    const int t = threadIdx.x;
    const int rowl = t >> 2, part = t & 3;        // 64 rows x 4 k-chunks of 16
    const int row = blockIdx.x * 64 + rowl;

    f32x4 acc[4] = {f32x4{0,0,0,0}, f32x4{0,0,0,0}, f32x4{0,0,0,0}, f32x4{0,0,0,0}};
#pragma unroll
    for (int s = 0; s < 8; ++s) {
        const float* base = wsy + ((size_t)s * 16384 + row) * 64 + part * 16;
#pragma unroll
        for (int u = 0; u < 4; ++u) acc[u] += *(const f32x4*)(base + u * 4);
    }
    float p = 0.f;
#pragma unroll
    for (int u = 0; u < 4; ++u) {
        p = fmaf(acc[u].x, acc[u].x, p);
        p = fmaf(acc[u].y, acc[u].y, p);
        p = fmaf(acc[u].z, acc[u].z, p);
        p = fmaf(acc[u].w, acc[u].w, p);
    }
    p += __shfl_xor(p, 1);
    p += __shfl_xor(p, 2);

    if (part == 0) {
        float z = 0.f;
#pragma unroll
        for (int s = 0; s < 8; ++s) z += wsz[(size_t)s * 16384 + row];
        out[row] = 0.5f * (p - z);
    }
}

extern "C" void kernel_launch(void* const* d_in, const int* in_sizes, int n_in,
                              void* d_out, int out_size, void* d_ws, size_t ws_size,
                              hipStream_t stream) {
    const float* x = (const float*)d_in[0];      // (16384, 1024) fp32
    const float* v = (const float*)d_in[1];      // (1024, 64) fp32
    float* out = (float*)d_out;                  // (16384, 1) fp32

    unsigned short* bh = (unsigned short*)d_ws;                    // 131072 B
    unsigned short* bl = (unsigned short*)((char*)d_ws + 131072);  // 131072 B
    float* wc  = (float*)((char*)d_ws + 262144);                   //   4096 B
    float* wsz = (float*)((char*)d_ws + 266240);                   // 524288 B (8*16384*4)
    float* wsy = (float*)((char*)d_ws + 790528);                   //  32 MiB (8*16384*64*4)

    const int B = in_sizes[0] / XD;              // 16384

    hipLaunchKernelGGL(prep_kernel, dim3(36), dim3(256), 0, stream, v, bh, bl, wc);
    hipLaunchKernelGGL(partial, dim3((B / 128) * 8), dim3(512), 0, stream,
                       x, bh, bl, wc, wsy, wsz);
    hipLaunchKernelGGL(finish, dim3(B / 64), dim3(256), 0, stream,
                       wsy, wsz, out);
}

// Round 12
// 98.811 us; speedup vs baseline: 1.4894x; 1.1321x over previous
//
#include <hip/hip_runtime.h>

// Problem: B=16384, X_DIM=1024, K=64, fp32 in/out.
// out[b] = 0.5 * ( sum_k (x_b . V[:,k])^2  -  sum_i x_bi^2 w_i ),  w_i = sum_k V[i][k]^2
//
// R12: R7 (best measured, 102.8) with the MFMA work quantum halved:
// single-product pure-bf16 (RNE on both x and V, no hi/lo compensation).
// Per tile: 4 frag b128 loads + 4 independent MFMAs (was 8 + 12) and ~14
// repack VALU (was ~30). Error budget: sigma(dy)~2.6e-3, dout ~ 0.05-0.2,
// + fp32-order noise ~0.3 -> absmax ~0.5-1.0 vs threshold 3.28.

typedef short short8 __attribute__((ext_vector_type(8)));   // 8 bf16 = 4 VGPRs
typedef float f32x4 __attribute__((ext_vector_type(4)));

constexpr int XD = 1024;
constexpr int KD = 64;

static __device__ __forceinline__ unsigned short f2bf(float f) {
    union { float f; unsigned u; } v; v.f = f;
    unsigned r = v.u + 0x7FFFu + ((v.u >> 16) & 1u);   // RNE
    return (unsigned short)(r >> 16);
}
static __device__ __forceinline__ unsigned fbits(float f) {
    union { float f; unsigned u; } v; v.f = f; return v.u;
}

// ---- prep: blocks 0..31 build bf16 B-fragments (RNE); 32..35 build w ----
// B-fragment layout (mfma_f32_16x16x32_bf16): lane l holds B[k=(l>>4)*8+j][n=l&15]
// ws: bh @ 0 (131072 B) | wc @ 131072 (4096 B)
__global__ void prep_kernel(const float* __restrict__ v,
                            unsigned short* __restrict__ bh,
                            float* __restrict__ wc) {
    if (blockIdx.x < 32) {
        int idx = blockIdx.x * 256 + threadIdx.x;
        int it = idx >> 8;
        int r  = idx & 255;
        int t  = r >> 6;
        int l  = r & 63;
        int q  = l >> 4, m = l & 15;
        int base_i = it * 32 + q * 8;
        int n = t * 16 + m;
        size_t fo = ((size_t)(it * 4 + t) * 64 + l) * 8;
#pragma unroll
        for (int j = 0; j < 8; ++j) {
            float val = v[(size_t)(base_i + j) * KD + n];
            bh[fo + j] = f2bf(val);
        }
    } else {
        int i = (blockIdx.x - 32) * 256 + threadIdx.x;   // 0..1023
        const f32x4* vp = (const f32x4*)(v + (size_t)i * KD);
        f32x4 tv[16];
#pragma unroll
        for (int qq = 0; qq < 16; ++qq) tv[qq] = vp[qq];
        float s = 0.f;
#pragma unroll
        for (int qq = 0; qq < 16; ++qq) {
            s = fmaf(tv[qq].x, tv[qq].x, s); s = fmaf(tv[qq].y, tv[qq].y, s);
            s = fmaf(tv[qq].z, tv[qq].z, s); s = fmaf(tv[qq].w, tv[qq].w, s);
        }
        wc[i] = s;
    }
}

// ---- main: 512 thr / 8 waves; block = 16 full rows; wave = 4 i-tiles ----
__global__ __launch_bounds__(512, 4)
void cross_r12(const float* __restrict__ x,
               const unsigned short* __restrict__ bh,
               const float* __restrict__ wc,
               float* __restrict__ out) {
    // xbuf: 16 rows x 256 float4 = 64 KB, XOR-swizzled at float4 granularity.
    // After a barrier, the front is reused as the 7-slot combine area.
    __shared__ f32x4 xb4[16 * 256];
    __shared__ float wlds[XD];         // 4 KB
    __shared__ float zb[7][16];

    const int tid = threadIdx.x;
    const int l = tid & 63;
    const int w = tid >> 6;            // wave 0..7
    const int q = l >> 4, m = l & 15;
    const int row0 = blockIdx.x * 16;

    // stage w (512 thr x float2, coalesced aligned)
    *(float2*)&wlds[tid * 2] = *(const float2*)(wc + tid * 2);

    // ---- stage x: 8 hoisted float4 loads/thread (64 KB in flight/block) ----
    f32x4 xv[8];
#pragma unroll
    for (int p = 0; p < 8; ++p) {
        int idx = p * 512 + tid;               // 0..4095 float4 slots
        int r = idx >> 8, c = idx & 255;
        xv[p] = *(const f32x4*)(x + (size_t)(row0 + r) * XD + c * 4);
    }
#pragma unroll
    for (int p = 0; p < 8; ++p) {
        int idx = p * 512 + tid;
        int r = idx >> 8, c = idx & 255;
        xb4[r * 256 + (c ^ (r & 7))] = xv[p];  // swizzled, 16B-aligned, bank-even
    }
    __syncthreads();

    // ---- compute: wave w -> i-tiles 4w .. 4w+3 ----
    f32x4 c4[4];
#pragma unroll
    for (int t = 0; t < 4; ++t) c4[t] = f32x4{0.f, 0.f, 0.f, 0.f};
    float z = 0.f;

    const short8* bhp = (const short8*)bh;

#pragma unroll
    for (int ii = 0; ii < 4; ++ii) {
        const int it = w * 4 + ii;
        const size_t fbase = (size_t)(it * 4) * 64 + l;

        // x fragment: row m, float4 slots it*8+q*2, +1 (swizzled read, bank-even)
        const int c0 = it * 8 + q * 2;
        f32x4 xa = xb4[m * 256 + (c0 ^ (m & 7))];
        f32x4 xb = xb4[m * 256 + ((c0 + 1) ^ (m & 7))];

        const float* wp = &wlds[it * 32 + q * 8];
        f32x4 wa = *(const f32x4*)wp, wb = *(const f32x4*)(wp + 4);
        float xs[8] = {xa.x, xa.y, xa.z, xa.w, xb.x, xb.y, xb.z, xb.w};
        z = fmaf(xs[0]*xs[0], wa.x, z); z = fmaf(xs[1]*xs[1], wa.y, z);
        z = fmaf(xs[2]*xs[2], wa.z, z); z = fmaf(xs[3]*xs[3], wa.w, z);
        z = fmaf(xs[4]*xs[4], wb.x, z); z = fmaf(xs[5]*xs[5], wb.y, z);
        z = fmaf(xs[6]*xs[6], wb.z, z); z = fmaf(xs[7]*xs[7], wb.w, z);

        // RNE bf16 pack of x (pairwise via v_perm)
        unsigned ahp[4];
#pragma unroll
        for (int jp = 0; jp < 4; ++jp) {
            unsigned u0 = fbits(xs[2 * jp]);
            unsigned u1 = fbits(xs[2 * jp + 1]);
            u0 += 0x7FFFu + ((u0 >> 16) & 1u);
            u1 += 0x7FFFu + ((u1 >> 16) & 1u);
            ahp[jp] = __builtin_amdgcn_perm(u1, u0, 0x07060302u);  // {hi16(u1),hi16(u0)}
        }
        short8 ah;
#pragma unroll
        for (int jp = 0; jp < 4; ++jp) {
            ah[2*jp]   = (short)(ahp[jp] & 0xFFFF);
            ah[2*jp+1] = (short)(ahp[jp] >> 16);
        }

        // 4 independent MFMA chains (one per col-tile t)
#pragma unroll
        for (int t = 0; t < 4; ++t) {
            short8 vh = bhp[fbase + (size_t)t * 64];
            c4[t] = __builtin_amdgcn_mfma_f32_16x16x32_bf16(ah, vh, c4[t], 0, 0, 0);
        }
    }

    // z: sum over q-chunks -> full-q partial z for row m (this wave's i-range)
    z += __shfl_xor(z, 16);
    z += __shfl_xor(z, 32);

    __syncthreads();   // all xbuf reads done; reuse as combine area
    float* comb = (float*)xb4;   // 7 slots x 64 lanes x 17 floats = 7616 <= 16384

    if (w > 0) {
        const int s = w - 1;
#pragma unroll
        for (int t = 0; t < 4; ++t)
#pragma unroll
            for (int r = 0; r < 4; ++r) comb[(s * 64 + l) * 17 + t * 4 + r] = c4[t][r];
        if (l < 16) zb[s][l] = z;
    }
    __syncthreads();

    if (w == 0) {
#pragma unroll
        for (int s = 0; s < 7; ++s) {
#pragma unroll
            for (int t = 0; t < 4; ++t)
#pragma unroll
                for (int r = 0; r < 4; ++r) c4[t][r] += comb[(s * 64 + l) * 17 + t * 4 + r];
            z += zb[s][m];
        }

        // C layout: col = l&15, row = q*4 + reg
        float p[4] = {0.f, 0.f, 0.f, 0.f};
#pragma unroll
        for (int r = 0; r < 4; ++r)
#pragma unroll
            for (int t = 0; t < 4; ++t) p[r] = fmaf(c4[t][r], c4[t][r], p[r]);
#pragma unroll
        for (int mask = 1; mask < 16; mask <<= 1)
#pragma unroll
            for (int r = 0; r < 4; ++r) p[r] += __shfl_xor(p[r], mask);

        float zrow = __shfl(z, q * 4 + m, 16);
        if (m < 4) out[row0 + q * 4 + m] = 0.5f * (p[m] - zrow);
    }
}

extern "C" void kernel_launch(void* const* d_in, const int* in_sizes, int n_in,
                              void* d_out, int out_size, void* d_ws, size_t ws_size,
                              hipStream_t stream) {
    const float* x = (const float*)d_in[0];      // (16384, 1024) fp32
    const float* v = (const float*)d_in[1];      // (1024, 64) fp32
    float* out = (float*)d_out;                  // (16384, 1) fp32

    unsigned short* bh = (unsigned short*)d_ws;                    // 131072 B
    float* wc = (float*)((char*)d_ws + 131072);                    //   4096 B

    const int B = in_sizes[0] / XD;              // 16384

    hipLaunchKernelGGL(prep_kernel, dim3(36), dim3(256), 0, stream, v, bh, wc);
    hipLaunchKernelGGL(cross_r12, dim3(B / 16), dim3(512), 0, stream,
                       x, bh, wc, out);
}